// Round 3
// baseline (569.478 us; speedup 1.0000x reference)
//
#include <hip/hip_runtime.h>
#include <cstdint>
#include <cstddef>

// Problem constants (GCMCLayer_70549132804177)
constexpr int kR   = 5;
constexpr int kNU  = 100000;
constexpr int kNM  = 100000;
constexpr int kE   = 1000000;
constexpr int kIN  = 64;
constexpr int kMSG = 80;
constexpr int kOUT = 64;
constexpr int kBAS = 4;
constexpr int kMPR = 16;   // kMSG / kR

constexpr int kN        = 100000;                  // nodes per side
constexpr int kNKEY     = 2 * kN * kR;             // 1,000,000 fine segments
constexpr unsigned kEdges = (unsigned)kR * (unsigned)kE;   // 5M per direction
constexpr unsigned kTotRecs = 2u * kEdges;         // 10M records

// Coarse bucketing: 512 dsts per bucket
constexpr int kNB        = (kN + 511) / 512;       // 196 buckets per direction
constexpr int kChunkE    = 4096;                   // edges per partition block
constexpr int kDirBlocks = (int)((kEdges + kChunkE - 1) / kChunkE);  // 1221
constexpr int kSegPerBkt = 512 * kR;               // 2560 fine segments/bucket
constexpr int kSlackPerBkt = kSegPerBkt * 3;       // max padding per bucket (7680)
constexpr unsigned kRecsCap = kTotRecs + (unsigned)(2 * kNB) * kSlackPerBkt + 16;

constexpr int kMsgBlocks = (kN + 255) / 256;       // 391

// Dummy plane indices (relative to each dir's plane base) -> shared zero line
// at absolute plane 2*kR*kN (the 64 B right after fi).
constexpr uint32_t kDummyRel0 = (uint32_t)(2 * kR * kN);  // dir 0 (base fu)
constexpr uint32_t kDummyRel1 = (uint32_t)(kR * kN);      // dir 1 (base fi)

// ---------------------------------------------------------------------------
// Kernel 1: per-node message precompute, both sides fused in one dispatch.
//   W[r,i,k] = sum_b att[r,b]*basis[b,i,k] (LDS, broadcast-read)
//   msg[r,node,k] = (sum_i feat[node,i]*W[r,i,k]) * cj[node]
// ---------------------------------------------------------------------------
__global__ __launch_bounds__(256) void gcmc_msg(
    const float* __restrict__ ufeat, const float* __restrict__ ifeat,
    const float* __restrict__ cj_user, const float* __restrict__ cj_movie,
    const float* __restrict__ att,  const float* __restrict__ basis,
    float* __restrict__ fu)                        // fi = fu + kR*kN*kMPR
{
    __shared__ float Wl[kR * kIN * kMPR];   // [r][i][k], k contiguous (20 KB)
    const int tid  = threadIdx.x;
    const int side = blockIdx.x >= kMsgBlocks;
    const int blk  = blockIdx.x - side * kMsgBlocks;
    const float* feat = side ? ifeat : ufeat;
    const float* cj   = side ? cj_movie : cj_user;
    float* msg = fu + (side ? (size_t)kR * kN * kMPR : 0);

    for (int idx = tid; idx < kR * kIN * kMPR; idx += 256) {
        const int r   = idx >> 10;
        const int rem = idx & 1023;
        const int i   = rem >> 4;
        const int k   = rem & 15;
        float s = 0.f;
#pragma unroll
        for (int b = 0; b < kBAS; ++b)
            s += att[r * kBAS + b] * basis[(b * kIN + i) * kMPR + k];
        Wl[idx] = s;
    }
    __syncthreads();

    const int node = blk * 256 + tid;
    if (node >= kN) return;

    float f[kIN];
    const float4* fp = reinterpret_cast<const float4*>(feat + (size_t)node * kIN);
#pragma unroll
    for (int i = 0; i < kIN / 4; ++i) {
        float4 v = fp[i];
        f[4 * i + 0] = v.x; f[4 * i + 1] = v.y;
        f[4 * i + 2] = v.z; f[4 * i + 3] = v.w;
    }
    const float c = cj[node];
    const float4* W4 = reinterpret_cast<const float4*>(Wl);
    float4* mout = reinterpret_cast<float4*>(msg);

    for (int r = 0; r < kR; ++r) {
#pragma unroll
        for (int kg = 0; kg < kMPR / 4; ++kg) {
            float4 a = make_float4(0.f, 0.f, 0.f, 0.f);
#pragma unroll
            for (int i = 0; i < kIN; ++i) {            // FULL unroll: f[i] static
                float4 w = W4[(r * kIN + i) * (kMPR / 4) + kg];
                a.x += f[i] * w.x; a.y += f[i] * w.y;
                a.z += f[i] * w.z; a.w += f[i] * w.w;
            }
            a.x *= c; a.y *= c; a.z *= c; a.w *= c;
            mout[((size_t)r * kN + node) * (kMPR / 4) + kg] = a;
        }
    }
}

// ---------------------------------------------------------------------------
// Phase A: coarse bucket counts (LDS histogram).
// ---------------------------------------------------------------------------
__global__ __launch_bounds__(256) void gcmc_bucket_count(
    const int* __restrict__ dst0, const int* __restrict__ dst1,
    uint32_t* __restrict__ bucket_count)
{
    __shared__ uint32_t h[kNB];
    const int tid = threadIdx.x;
    const int dir = blockIdx.x >= kDirBlocks;
    const int blk = blockIdx.x - dir * kDirBlocks;
    const int* dsts = dir ? dst1 : dst0;
    for (int i = tid; i < kNB; i += 256) h[i] = 0;
    __syncthreads();
    const unsigned base = (unsigned)blk * kChunkE;
#pragma unroll
    for (int j = 0; j < kChunkE / 256; ++j) {
        const unsigned idx = base + j * 256u + tid;
        if (idx < kEdges) atomicAdd(&h[(unsigned)dsts[idx] >> 9], 1u);
    }
    __syncthreads();
    for (int i = tid; i < kNB; i += 256) {
        const uint32_t c = h[i];
        if (c) atomicAdd(&bucket_count[dir * kNB + i], c);
    }
}

// ---------------------------------------------------------------------------
// Phase B: exclusive scan of 392 bucket counts -> bucket_base, cursor.
// ---------------------------------------------------------------------------
__global__ __launch_bounds__(512) void gcmc_bucket_scan(
    const uint32_t* __restrict__ bucket_count,
    uint32_t* __restrict__ bucket_base, uint32_t* __restrict__ cursor)
{
    __shared__ uint32_t sh[512];
    const int t = threadIdx.x;
    const uint32_t mine = (t < 2 * kNB) ? bucket_count[t] : 0u;
    sh[t] = mine; __syncthreads();
    for (int off = 1; off < 512; off <<= 1) {
        const uint32_t v = (t >= off) ? sh[t - off] : 0u;
        __syncthreads();
        sh[t] += v;
        __syncthreads();
    }
    if (t < 2 * kNB) { bucket_base[t] = sh[t] - mine; cursor[t] = sh[t] - mine; }
    if (t == 2 * kNB - 1) bucket_base[2 * kNB] = sh[t];
}

// ---------------------------------------------------------------------------
// Phase C: LDS-staged partition (multisplit) -> coalesced bucket_recs writes.
// Packed record: src[0:16] | dst_local[17:25] | r[26:28].
// ---------------------------------------------------------------------------
__global__ __launch_bounds__(256) void gcmc_partition(
    const int* __restrict__ dst0, const int* __restrict__ src0,
    const int* __restrict__ dst1, const int* __restrict__ src1,
    uint32_t* __restrict__ cursor, uint32_t* __restrict__ bucket_recs)
{
    __shared__ uint32_t hist[kNB];
    __shared__ uint32_t excl[kNB];
    __shared__ uint32_t gbase[kNB];
    __shared__ uint32_t scanT[256];
    __shared__ uint32_t stage[kChunkE];     // 16 KB
    __shared__ uint8_t  sbkt[kChunkE];      // 4 KB
    const int tid = threadIdx.x;
    const int dir = blockIdx.x >= kDirBlocks;
    const int blk = blockIdx.x - dir * kDirBlocks;
    const int* dsts = dir ? dst1 : dst0;
    const int* srcs = dir ? src1 : src0;

    for (int i = tid; i < kNB; i += 256) hist[i] = 0;
    __syncthreads();

    const unsigned base = (unsigned)blk * kChunkE;
    uint32_t rec[16], bk[16], rk[16];
#pragma unroll
    for (int j = 0; j < 16; ++j) {
        const unsigned idx = base + j * 256u + tid;
        if (idx < kEdges) {
            const unsigned d = (unsigned)dsts[idx];
            const unsigned s = (unsigned)srcs[idx];
            const unsigned r = idx / (unsigned)kE;     // magic-mul
            rec[j] = s | ((d & 511u) << 17) | (r << 26);
            bk[j]  = d >> 9;
            rk[j]  = atomicAdd(&hist[bk[j]], 1u);      // local rank in bucket
        } else bk[j] = 0xFFFFFFFFu;
    }
    __syncthreads();

    const uint32_t c = (tid < kNB) ? hist[tid] : 0u;
    scanT[tid] = c; __syncthreads();
    for (int off = 1; off < 256; off <<= 1) {
        const uint32_t v = (tid >= off) ? scanT[tid - off] : 0u;
        __syncthreads();
        scanT[tid] += v;
        __syncthreads();
    }
    const uint32_t total = scanT[255];
    if (tid < kNB) {
        excl[tid]  = scanT[tid] - c;
        gbase[tid] = c ? atomicAdd(&cursor[dir * kNB + tid], c) : 0u;
    }
    __syncthreads();

#pragma unroll
    for (int j = 0; j < 16; ++j) {
        if (bk[j] != 0xFFFFFFFFu) {
            const uint32_t p = excl[bk[j]] + rk[j];
            stage[p] = rec[j];
            sbkt[p]  = (uint8_t)bk[j];
        }
    }
    __syncthreads();

    for (unsigned p = tid; p < total; p += 256) {      // coalesced copy-out
        const uint32_t b = sbkt[p];
        bucket_recs[gbase[b] + (p - excl[b])] = stage[p];
    }
}

// ---------------------------------------------------------------------------
// Phase D: per-bucket fine sort with 4-ALIGNED PADDED segments.
// One block per (dir,bucket); LDS hist -> padded scan -> node_start/
// seg_pcount -> scatter (L2-resident region) -> dummy-pad fill.
// Output record: relative plane index r*kN + src (dummy -> zero line).
// Bucket db's output region: bucket_base[db] + db*kSlackPerBkt (slack gaps
// between buckets are NEVER walked -- gather uses node_start+seg_pcount).
// ---------------------------------------------------------------------------
__global__ __launch_bounds__(512) void gcmc_bucket_sort(
    const uint32_t* __restrict__ bucket_recs,
    const uint32_t* __restrict__ bucket_base,
    uint32_t* __restrict__ node_start, uint32_t* __restrict__ seg_pcount,
    uint32_t* __restrict__ recs)
{
    __shared__ uint32_t ps[kSegPerBkt + 1];   // padded starts (global) 10.2 KB
    __shared__ uint32_t cur[kSegPerBkt];      // hist, then cursor (10 KB)
    __shared__ uint32_t scanT[512];
    const int tid = threadIdx.x;
    const int db  = blockIdx.x;                 // 0..2*kNB-1
    const int dir = db >= kNB;
    const int bl  = db - dir * kNB;
    const uint32_t gb0 = bucket_base[db], gb1 = bucket_base[db + 1];
    const uint32_t obase = gb0 + (uint32_t)db * kSlackPerBkt;
    const int dstBase = bl << 9;
    const int ndst = (kN - dstBase < 512) ? (kN - dstBase) : 512;
    const int nseg = ndst * kR;

    for (int i = tid; i < kSegPerBkt; i += 512) cur[i] = 0;
    __syncthreads();

    for (uint32_t i = gb0 + tid; i < gb1; i += 512) {
        const uint32_t rec = bucket_recs[i];
        atomicAdd(&cur[((rec >> 17) & 511u) * kR + (rec >> 26)], 1u);
    }
    __syncthreads();

    // padded exclusive scan: 512 threads x 5 consecutive segments
    uint32_t loc[5]; uint32_t s = 0;
#pragma unroll
    for (int q = 0; q < 5; ++q) {
        loc[q] = (cur[tid * 5 + q] + 3u) & ~3u;        // pad to multiple of 4
        s += loc[q];
    }
    scanT[tid] = s; __syncthreads();
    for (int off = 1; off < 512; off <<= 1) {
        const uint32_t v = (tid >= off) ? scanT[tid - off] : 0u;
        __syncthreads();
        scanT[tid] += v;
        __syncthreads();
    }
    uint32_t run = obase + scanT[tid] - s;
#pragma unroll
    for (int q = 0; q < 5; ++q) { ps[tid * 5 + q] = run; run += loc[q]; }
    if (tid == 511) ps[kSegPerBkt] = run;
    __syncthreads();

    const uint32_t keybase = ((uint32_t)dir * kN + (uint32_t)dstBase) * kR;
    for (int sg = tid; sg < nseg; sg += 512) {
        cur[sg] = ps[sg];                              // cursor = padded start
        seg_pcount[keybase + sg] = ps[sg + 1] - ps[sg];
    }
    for (int dl = tid; dl < ndst; dl += 512)
        node_start[dir * kN + dstBase + dl] = ps[dl * kR];
    __syncthreads();

    for (uint32_t i = gb0 + tid; i < gb1; i += 512) {
        const uint32_t rec = bucket_recs[i];
        const uint32_t r   = rec >> 26;
        const uint32_t seg = ((rec >> 17) & 511u) * kR + r;
        const uint32_t pos = atomicAdd(&cur[seg], 1u);
        recs[pos] = (rec & 0x1FFFFu) + r * (uint32_t)kN;
    }
    __syncthreads();

    const uint32_t dummy = dir ? kDummyRel1 : kDummyRel0;
    for (int sg = tid; sg < nseg; sg += 512) {
        const uint32_t e = ps[sg + 1];
        for (uint32_t p = cur[sg]; p < e; ++p) recs[p] = dummy;  // <=3 iters
    }
}

// ---------------------------------------------------------------------------
// Kernel 3: wave-per-node gather + fused ci*relu*FC.
// 64 lanes = 4 record slots x 16 message cols. 5 static per-r sub-loops
// share a 3-deep software pipeline (recs 4 batches ahead, msg lines 3
// ahead); segments are 4-aligned so batches never straddle -> static accs,
// no selects, no tails, no intra-wave divergence. Cross-slot shfl reduce,
// then lane=o FC with conflict-free Wq[jj][o][4] layout. No barrier between
// gather and FC (per-wave LDS row).
// ---------------------------------------------------------------------------
__global__ __launch_bounds__(1024) void gcmc_gather_fc(
    const float* __restrict__ fu,              // fi = fu + kR*kN*kMPR
    const uint32_t* __restrict__ recs,
    const uint32_t* __restrict__ node_start,
    const uint32_t* __restrict__ seg_pcount,
    const float* __restrict__ ci_user, const float* __restrict__ ci_movie,
    const float* __restrict__ fc_w, const float* __restrict__ fc_b,
    float* __restrict__ out_u, float* __restrict__ out_m)
{
    __shared__ float Wq[20 * kOUT * 4];  // [jj][o][q] = fc_w[o][jj*4+q] (20 KB)
    __shared__ float Bl[kOUT];
    __shared__ float Xs[16][kMSG];       // one row per wave (5 KB)
    const int tid = threadIdx.x;
    for (int idx = tid; idx < 20 * kOUT * 4; idx += 1024) {
        const int q  = idx & 3;
        const int o  = (idx >> 2) & 63;
        const int jj = idx >> 8;
        Wq[idx] = fc_w[o * kMSG + jj * 4 + q];   // consecutive LDS words: no conflict
    }
    if (tid < kOUT) Bl[tid] = fc_b[tid];
    __syncthreads();

    const int col  = tid & 15;
    const int slot = (tid >> 4) & 3;
    const int w    = tid >> 6;
    const int node = blockIdx.x * 16 + w;        // 0..2*kN-1, grid exact
    const int dir  = node >= kN;                 // 0: dst=movie, 1: dst=user
    const int d    = dir ? node - kN : node;
    const float* plane = fu + (dir ? (size_t)kR * kN * kMPR : 0) + col;
    const uint32_t uclamp = dir ? kDummyRel1 : kDummyRel0;  // OOB-prefetch safety

    uint32_t j = (uint32_t)__builtin_amdgcn_readfirstlane((int)node_start[node]);
    const int sb = node * kR;
    const uint32_t b1 = j  + (uint32_t)__builtin_amdgcn_readfirstlane((int)seg_pcount[sb + 0]);
    const uint32_t b2 = b1 + (uint32_t)__builtin_amdgcn_readfirstlane((int)seg_pcount[sb + 1]);
    const uint32_t b3 = b2 + (uint32_t)__builtin_amdgcn_readfirstlane((int)seg_pcount[sb + 2]);
    const uint32_t b4 = b3 + (uint32_t)__builtin_amdgcn_readfirstlane((int)seg_pcount[sb + 3]);
    const uint32_t b5 = b4 + (uint32_t)__builtin_amdgcn_readfirstlane((int)seg_pcount[sb + 4]);

    // 3-deep pipeline prologue (clamped prefetch may overrun into slack/pads;
    // values are loaded but never accumulated)
    uint32_t jj = j + slot;
    uint32_t t0 = recs[jj];      uint32_t u0 = t0 < uclamp ? t0 : uclamp;
    uint32_t t1 = recs[jj + 4];  uint32_t u1 = t1 < uclamp ? t1 : uclamp;
    float v0 = plane[(size_t)u0 * kMPR];
    uint32_t t2 = recs[jj + 8];  uint32_t u2 = t2 < uclamp ? t2 : uclamp;
    float v1 = plane[(size_t)u1 * kMPR];
    uint32_t t3 = recs[jj + 12]; uint32_t u3 = t3 < uclamp ? t3 : uclamp;
    float v2 = plane[(size_t)u2 * kMPR];

    float a0 = 0.f, a1 = 0.f, a2 = 0.f, a3 = 0.f, a4 = 0.f;
#define GSTEP(AC)  { uint32_t tn = recs[jj + 16];                     \
                     uint32_t un = tn < uclamp ? tn : uclamp;         \
                     float vn = plane[(size_t)u3 * kMPR];             \
                     AC += v0; v0 = v1; v1 = v2; v2 = vn; u3 = un;    \
                     jj += 4; j += 4; }
    while (j < b1) { GSTEP(a0) }
    while (j < b2) { GSTEP(a1) }
    while (j < b3) { GSTEP(a2) }
    while (j < b4) { GSTEP(a3) }
    while (j < b5) { GSTEP(a4) }
#undef GSTEP

    // cross-slot reduce (sum the 4 slots' partials)
    a0 += __shfl_xor(a0, 16); a0 += __shfl_xor(a0, 32);
    a1 += __shfl_xor(a1, 16); a1 += __shfl_xor(a1, 32);
    a2 += __shfl_xor(a2, 16); a2 += __shfl_xor(a2, 32);
    a3 += __shfl_xor(a3, 16); a3 += __shfl_xor(a3, 32);
    a4 += __shfl_xor(a4, 16); a4 += __shfl_xor(a4, 32);

    const float c = dir ? ci_user[d] : ci_movie[d];
    const float x0 = fmaxf(a0 * c, 0.f);
    const float x1 = fmaxf(a1 * c, 0.f);
    const float x2 = fmaxf(a2 * c, 0.f);
    const float x3 = fmaxf(a3 * c, 0.f);
    const float x4 = fmaxf(a4 * c, 0.f);

    // slot s writes r=s (64 consecutive words, conflict-free); slot 0 adds r=4
    const float xs = (slot == 0) ? x0 : (slot == 1) ? x1 : (slot == 2) ? x2 : x3;
    Xs[w][slot * kMPR + col] = xs;
    if (slot == 0) Xs[w][4 * kMPR + col] = x4;
    // no barrier: same-wave LDS RAW is ordered via lgkmcnt

    // FC: lane o computes out[o]; Wq read = contiguous 1024 B per wave
    const int o = tid & 63;
    const float4* X4 = reinterpret_cast<const float4*>(&Xs[w][0]);
    const float4* W4 = reinterpret_cast<const float4*>(Wq);
    float acc = Bl[o];
#pragma unroll
    for (int t = 0; t < 20; ++t) {
        const float4 xv = X4[t];            // broadcast (same addr all lanes)
        const float4 wv = W4[t * 64 + o];
        acc += xv.x * wv.x + xv.y * wv.y + xv.z * wv.z + xv.w * wv.w;
    }
    float* outp = dir ? out_u : out_m;
    outp[(size_t)d * kOUT + o] = acc;
}

// ---------------------------------------------------------------------------
extern "C" void kernel_launch(void* const* d_in, const int* in_sizes, int n_in,
                              void* d_out, int out_size, void* d_ws, size_t ws_size,
                              hipStream_t stream) {
    const float* ufeat    = (const float*)d_in[0];
    const float* ifeat    = (const float*)d_in[1];
    const float* cj_user  = (const float*)d_in[2];
    const float* ci_user  = (const float*)d_in[3];
    const float* cj_movie = (const float*)d_in[4];
    const float* ci_movie = (const float*)d_in[5];
    const int*   edge_user  = (const int*)d_in[6];
    const int*   edge_movie = (const int*)d_in[7];
    const float* att   = (const float*)d_in[8];
    const float* basis = (const float*)d_in[9];
    const float* fc_w  = (const float*)d_in[10];
    const float* fc_b  = (const float*)d_in[11];

    float* out_u = (float*)d_out;                    // [NU][64]
    float* out_m = out_u + (size_t)kNU * kOUT;       // [NM][64]

    // Workspace (~121 MB):
    //   fu/fi  [2][R][N][16] f32 = 64 MB  (+ one 64 B zero line)
    //   recs   [kRecsCap]    u32 = 52 MB  (4-aligned padded segments + slack)
    //   node_start [2N]      u32 = 0.8 MB
    //   seg_pcount [1M]      u32 = 4 MB
    float* fu = (float*)d_ws;
    float* zline = fu + (size_t)2 * kR * kN * kMPR;            // 16 floats
    uint32_t* recs       = (uint32_t*)(zline + kMPR);
    uint32_t* node_start = recs + kRecsCap;
    uint32_t* seg_pcount = node_start + 2 * kN;

    // Sort scratch in d_out (40 MB < 51.2 MB), fully overwritten by gather:
    uint32_t* bucket_recs  = (uint32_t*)d_out;
    uint32_t* bucket_count = bucket_recs + (size_t)kTotRecs;
    uint32_t* bucket_base  = bucket_count + 2 * kNB;   // 2*kNB+1 entries
    uint32_t* cursorC      = bucket_base + 2 * kNB + 1;

    hipMemsetAsync(bucket_count, 0, (size_t)(2 * kNB) * sizeof(uint32_t), stream);
    hipMemsetAsync(zline, 0, kMPR * sizeof(float), stream);

    gcmc_msg<<<2 * kMsgBlocks, 256, 0, stream>>>(
        ufeat, ifeat, cj_user, cj_movie, att, basis, fu);

    // dir 0: user -> movie (dst = movie); dir 1: movie -> user (dst = user)
    gcmc_bucket_count<<<2 * kDirBlocks, 256, 0, stream>>>(
        edge_movie, edge_user, bucket_count);
    gcmc_bucket_scan<<<1, 512, 0, stream>>>(bucket_count, bucket_base, cursorC);
    gcmc_partition<<<2 * kDirBlocks, 256, 0, stream>>>(
        edge_movie, edge_user, edge_user, edge_movie, cursorC, bucket_recs);
    gcmc_bucket_sort<<<2 * kNB, 512, 0, stream>>>(
        bucket_recs, bucket_base, node_start, seg_pcount, recs);

    gcmc_gather_fc<<<(2 * kN) / 16, 1024, 0, stream>>>(
        fu, recs, node_start, seg_pcount, ci_user, ci_movie,
        fc_w, fc_b, out_u, out_m);
}